// Round 3
// baseline (148.178 us; speedup 1.0000x reference)
//
#include <hip/hip_runtime.h>

// B=32, T=2048, D=64, K=4, KD=256
// out[b,t,j] = m*ha + (1-m)*(g*h_fwd + (1-g)*ha)
//   d = j % 64, m = M[b,t,d], delta = deltas[b,t,d] in {1,2,3,4} (clamped <= t+1)
//   g = exp(-relu(delta*W[j] + b[j]))
//   h_fwd = h_a[b, t-(int(delta)-1), j]  -> one of rows t, t-1, t-2, t-3
//
// v4: v1 shape (best measured: one f32x4 per thread, 16384 blocks, all loads
// independent) with ONE change: regular cache-allocating store instead of
// __builtin_nontemporal_store.
//   Rationale: across v1/v2/v3, FETCH bytes (-17%), VMEM instrs (-35%),
//   and occupancy shape were each varied with zero effect on duration; the
//   only untested structural difference vs the 6.29 TB/s float4-copy ceiling
//   is the nt store, which pins WRITE_SIZE at exactly 64 MB/dispatch (no
//   L2/L3 write absorption; working set 160 MB < 256 MB L3).

#define TD_T 2048
#define TD_KD 256
#define TD_D 64

typedef float f32x4 __attribute__((ext_vector_type(4)));

__global__ __launch_bounds__(256) void TemporalDecay_89524298318172_kernel(
    const float* __restrict__ h_a,
    const float* __restrict__ deltas,
    const float* __restrict__ M,
    const float* __restrict__ W,
    const float* __restrict__ bias,
    float* __restrict__ out)
{
    const int gid = blockIdx.x * blockDim.x + threadIdx.x;
    const int q   = gid & 63;        // which float4 within the 256-wide row
    const int row = gid >> 6;        // b*T + t
    const int t   = row & (TD_T - 1);
    const int j0  = q << 2;          // 0..252, multiple of 4
    const int d0  = j0 & (TD_D - 1); // no wrap inside a float4 (4 | 64)

    const size_t row_off = (size_t)row * TD_KD + j0;

    // All loads issue with no inter-load dependencies.
    const f32x4 ha4 = *(const f32x4*)(h_a    + row_off);
    const f32x4 m4  = *(const f32x4*)(M      + (size_t)row * TD_D + d0);
    const f32x4 dl4 = *(const f32x4*)(deltas + (size_t)row * TD_D + d0);
    const f32x4 w4  = *(const f32x4*)(W    + j0);
    const f32x4 b4  = *(const f32x4*)(bias + j0);

    // Candidate rows t-1, t-2, t-3 (clamped; unselected when t-r < 0 since
    // delta <= t+1 guarantees the selected row index is >= 0).
    const int r1 = (t >= 1) ? t - 1 : 0;
    const int r2 = (t >= 2) ? t - 2 : 0;
    const int r3 = (t >= 3) ? t - 3 : 0;
    const size_t bt_base = (size_t)(row - t) * TD_KD + j0;  // b*T*KD + j0
    const f32x4 c1 = *(const f32x4*)(h_a + bt_base + (size_t)r1 * TD_KD);
    const f32x4 c2 = *(const f32x4*)(h_a + bt_base + (size_t)r2 * TD_KD);
    const f32x4 c3 = *(const f32x4*)(h_a + bt_base + (size_t)r3 * TD_KD);

    f32x4 res;
#pragma unroll
    for (int e = 0; e < 4; ++e) {
        const float delta = dl4[e];
        const float g = __expf(-fmaxf(fmaf(delta, w4[e], b4[e]), 0.0f));
        const int di = (int)delta;  // 1..4
        float hf = ha4[e];
        hf = (di == 2) ? c1[e] : hf;
        hf = (di == 3) ? c2[e] : hf;
        hf = (di == 4) ? c3[e] : hf;
        const float m = m4[e];
        res[e] = m * ha4[e] + (1.0f - m) * (g * hf + (1.0f - g) * ha4[e]);
    }

    // Regular (cache-allocating) store — the single change vs v1.
    *(f32x4*)(out + row_off) = res;
}

extern "C" void kernel_launch(void* const* d_in, const int* in_sizes, int n_in,
                              void* d_out, int out_size, void* d_ws, size_t ws_size,
                              hipStream_t stream) {
    const float* h_a    = (const float*)d_in[0];
    const float* deltas = (const float*)d_in[1];
    const float* M      = (const float*)d_in[2];
    const float* W      = (const float*)d_in[3];
    const float* bias   = (const float*)d_in[4];
    float* out          = (float*)d_out;

    // total float4 threads = B*T*KD/4 = 4,194,304
    const int total = in_sizes[0] / 4;
    const int block = 256;
    const int grid = (total + block - 1) / block;  // 16384
    TemporalDecay_89524298318172_kernel<<<grid, block, 0, stream>>>(
        h_a, deltas, M, W, bias, out);
}